// Round 7
// baseline (668.608 us; speedup 1.0000x reference)
//
#include <hip/hip_runtime.h>

#define BS 256
#define NB 128          // dst-range buckets
#define CHUNK 4096      // edges per phase-1 block
#define CAP 96          // slots per (block,bucket); Poisson(32) tail ~1e-13
#define OVF_CAP 65536

using half4 = __attribute__((ext_vector_type(4))) _Float16;

template<typename T>
__device__ __forceinline__ float4 load4(const T* p) {
    if constexpr (sizeof(T) == 4) {
        return *(const float4*)p;
    } else {
        half4 v = *(const half4*)p;
        return make_float4((float)v.x, (float)v.y, (float)v.z, (float)v.w);
    }
}
template<typename T>
__device__ __forceinline__ void store4(T* p, float4 v) {
    if constexpr (sizeof(T) == 4) {
        *(float4*)p = v;
    } else {
        half4 h = {(_Float16)v.x, (_Float16)v.y, (_Float16)v.z, (_Float16)v.w};
        *(half4*)p = h;
    }
}

// ---------------- CSR build ----------------

__global__ __launch_bounds__(BS) void k_zero(int* a, int* b, int* c, int n) {
    int i = blockIdx.x * BS + threadIdx.x;
    if (i < n) { a[i] = 0; b[i] = 0; }
    if (i == 0) *c = 0;
}

// Phase 1: histogram + bucket edges into block-private regions.
// Writes are block-exclusive -> no cross-XCD partial-line writebacks.
__global__ __launch_bounds__(BS) void k_bucket(const int* __restrict__ src, const int* __restrict__ dst,
                                               int* __restrict__ cnt, unsigned* __restrict__ bbuf,
                                               int* __restrict__ bcounts, uint2* __restrict__ ovf,
                                               int* __restrict__ ovf_cnt,
                                               int E, unsigned long long invB, int bsz) {
    __shared__ int lcnt[NB];
    for (int t = threadIdx.x; t < NB; t += BS) lcnt[t] = 0;
    __syncthreads();
    int base_e = blockIdx.x * CHUNK;
    unsigned* mybuf = bbuf + (size_t)blockIdx.x * NB * CAP;
    #pragma unroll
    for (int j = 0; j < CHUNK / BS; ++j) {
        int e = base_e + j * BS + threadIdx.x;
        if (e < E) {
            int d = dst[e];
            int s = src[e];
            atomicAdd(&cnt[d], 1);                       // fire-and-forget
            int b = (int)(((unsigned long long)(unsigned)d * invB) >> 40);
            int doff = d - b * bsz;                      // < 1024
            int pos = atomicAdd(&lcnt[b], 1);
            if (pos < CAP) {
                mybuf[b * CAP + pos] = ((unsigned)doff << 17) | (unsigned)s;  // s < 2^17
            } else {
                int op = atomicAdd(ovf_cnt, 1);
                if (op < OVF_CAP) ovf[op] = make_uint2((unsigned)s, (unsigned)d);
            }
        }
    }
    __syncthreads();
    for (int t = threadIdx.x; t < NB; t += BS)
        bcounts[blockIdx.x * NB + t] = min(lcnt[t], CAP);
}

__global__ __launch_bounds__(BS) void k_dinv(const int* __restrict__ cnt, float* __restrict__ dinv, int N) {
    int i = blockIdx.x * BS + threadIdx.x;
    if (i < N) dinv[i] = rsqrtf((float)(cnt[i] + 1));   // +1 = self-loop
}

__global__ __launch_bounds__(BS) void k_scan1(const int* __restrict__ cnt, int* __restrict__ bsum, int N) {
    __shared__ int s[BS];
    int i = blockIdx.x * BS + threadIdx.x;
    s[threadIdx.x] = (i < N) ? cnt[i] : 0;
    __syncthreads();
    for (int off = BS / 2; off > 0; off >>= 1) {
        if (threadIdx.x < off) s[threadIdx.x] += s[threadIdx.x + off];
        __syncthreads();
    }
    if (threadIdx.x == 0) bsum[blockIdx.x] = s[0];
}

__global__ __launch_bounds__(512) void k_scan2(int* bsum, int nb) {
    __shared__ int s[512];
    int t = threadIdx.x;
    int v = (t < nb) ? bsum[t] : 0;
    s[t] = v;
    __syncthreads();
    for (int off = 1; off < 512; off <<= 1) {
        int u = (t >= off) ? s[t - off] : 0;
        __syncthreads();
        s[t] += u;
        __syncthreads();
    }
    if (t < nb) bsum[t] = s[t] - v;   // exclusive of self
}

__global__ __launch_bounds__(BS) void k_scan3(const int* __restrict__ cnt, const int* __restrict__ boff,
                                              int* __restrict__ row_ptr, int N) {
    __shared__ int s[BS];
    int t = threadIdx.x;
    int i = blockIdx.x * BS + t;
    int v = (i < N) ? cnt[i] : 0;
    s[t] = v;
    __syncthreads();
    for (int off = 1; off < BS; off <<= 1) {
        int u = (t >= off) ? s[t - off] : 0;
        __syncthreads();
        s[t] += u;
        __syncthreads();
    }
    int base = boff[blockIdx.x];
    if (i < N) row_ptr[i] = base + s[t] - v;
    if (i == N - 1) row_ptr[N] = base + s[t];
}

// Phase 2: one block per bucket; scatter into its ~100KB CSR entry region
// (single-block-exclusive -> stays in that CU's XCD L2, dense writeback).
__global__ __launch_bounds__(BS) void k_fill2(const unsigned* __restrict__ bbuf, const int* __restrict__ bcounts,
                                              const uint2* __restrict__ ovf, const int* __restrict__ ovf_cnt,
                                              const int* __restrict__ row_ptr, int* __restrict__ fillpos,
                                              const float* __restrict__ dinv, uint2* __restrict__ entries,
                                              int nch, int bsz) {
    int b = blockIdx.x;
    int lo = b * bsz;
    int wid = threadIdx.x >> 6, lane = threadIdx.x & 63;
    for (int r = wid; r < nch; r += BS / 64) {
        int c = bcounts[r * NB + b];                    // wave-uniform
        const unsigned* seg = bbuf + ((size_t)r * NB + b) * CAP;
        for (int k = lane; k < c; k += 64) {
            unsigned u = seg[k];
            int s = (int)(u & 0x1FFFFu);
            int d = lo + (int)(u >> 17);
            float w = dinv[s] * dinv[d];
            int pos = row_ptr[d] + atomicAdd(&fillpos[d], 1);
            entries[pos] = make_uint2((unsigned)s, __float_as_uint(w));
        }
    }
    int novf = min(*ovf_cnt, OVF_CAP);                  // ~0 in practice
    for (int j = blockIdx.x * BS + threadIdx.x; j < novf; j += (int)gridDim.x * BS) {
        uint2 e = ovf[j];
        int s = (int)e.x, d = (int)e.y;
        float w = dinv[s] * dinv[d];
        int pos = row_ptr[d] + atomicAdd(&fillpos[d], 1);
        entries[pos] = make_uint2((unsigned)s, __float_as_uint(w));
    }
}

// ---------------- dense transform ----------------
// out[N, LDOUT(pad0)] = H[N, LDIN] @ W[K, M] (+bias)(+relu). Single pass,
// full-M accumulators; W in LDS read via same-address broadcast.
template<typename TIN, int K, int M, int LDIN, int LDOUT, bool BIAS, bool RELU, typename TOUT>
__global__ __launch_bounds__(BS) void k_gemm(const TIN* __restrict__ H, const float* __restrict__ Wg,
                                             const float* __restrict__ bias, TOUT* __restrict__ out, int N) {
    constexpr int M4 = (M + 3) & ~3;
    __shared__ float Wl[K * M4];
    for (int idx = threadIdx.x; idx < K * M4; idx += BS) {
        int k = idx / M4, m = idx - k * M4;
        Wl[idx] = (m < M) ? Wg[(size_t)k * M + m] : 0.f;
    }
    __syncthreads();

    int row = blockIdx.x * BS + threadIdx.x;
    bool ok = row < N;
    int rr = ok ? row : (N - 1);            // clamp: safe loads, masked stores
    const TIN* hp = H + (size_t)rr * LDIN;

    float acc[M4];
    #pragma unroll
    for (int m = 0; m < M4; ++m) acc[m] = 0.f;

    constexpr int K4 = K & ~3;
    #pragma unroll 2
    for (int k = 0; k < K4; k += 4) {
        float4 hv = load4(hp + k);
        const float h[4] = {hv.x, hv.y, hv.z, hv.w};
        #pragma unroll
        for (int j = 0; j < 4; ++j) {
            const float* wl = &Wl[(k + j) * M4];
            #pragma unroll
            for (int m = 0; m < M4; m += 4) {
                float4 w = *(const float4*)(wl + m);   // ds_read_b128 broadcast
                acc[m + 0] = fmaf(h[j], w.x, acc[m + 0]);
                acc[m + 1] = fmaf(h[j], w.y, acc[m + 1]);
                acc[m + 2] = fmaf(h[j], w.z, acc[m + 2]);
                acc[m + 3] = fmaf(h[j], w.w, acc[m + 3]);
            }
        }
    }
    #pragma unroll
    for (int k = K4; k < K; ++k) {
        float h = (float)hp[k];
        const float* wl = &Wl[k * M4];
        #pragma unroll
        for (int m = 0; m < M4; m += 4) {
            float4 w = *(const float4*)(wl + m);
            acc[m + 0] = fmaf(h, w.x, acc[m + 0]);
            acc[m + 1] = fmaf(h, w.y, acc[m + 1]);
            acc[m + 2] = fmaf(h, w.z, acc[m + 2]);
            acc[m + 3] = fmaf(h, w.w, acc[m + 3]);
        }
    }

    if (!ok) return;
    TOUT* op = out + (size_t)row * LDOUT;
    #pragma unroll
    for (int g = 0; g < LDOUT / 4; ++g) {
        int cb = 4 * g;
        float4 v;
        float* vp = &v.x;
        #pragma unroll
        for (int j = 0; j < 4; ++j) {
            int c = cb + j;
            float x = (c < M) ? acc[(c < M4) ? c : 0] : 0.f;
            if (BIAS && c < M) x += bias[c];
            if (RELU) x = fmaxf(x, 0.f);
            vp[j] = x;
        }
        store4(op + cb, v);
    }
}

// ---------------- normalized aggregation ----------------
// out[i,:] = dinv_i^2*T[i,:] + sum_e w_e * T[src_e,:]  (+bias)(+relu)
template<typename TIN, typename TOUT, int M, int M4, int LDI, int LDO, bool BIAS, bool RELU>
__global__ __launch_bounds__(BS) void k_agg(const TIN* __restrict__ T, TOUT* __restrict__ out,
                                            const int* __restrict__ row_ptr, const uint2* __restrict__ entries,
                                            const float* __restrict__ dinv, const float* __restrict__ bias,
                                            int N) {
    constexpr int CG = M4 / 4;
    int idx = blockIdx.x * BS + threadIdx.x;
    if (idx >= N * CG) return;
    int i  = idx / CG;                // const divisor -> magic mul
    int cg = idx - i * CG;
    int c0 = cg * 4;

    float di = dinv[i];
    float4 t0 = load4(T + (size_t)i * LDI + c0);
    float w0 = di * di;
    float4 acc0 = make_float4(w0 * t0.x, w0 * t0.y, w0 * t0.z, w0 * t0.w);
    float4 acc1 = make_float4(0.f, 0.f, 0.f, 0.f);

    int e0 = row_ptr[i], e1 = row_ptr[i + 1];
    int e = e0;
    for (; e + 3 < e1; e += 4) {
        uint2 ea = entries[e];
        uint2 eb = entries[e + 1];
        uint2 ec = entries[e + 2];
        uint2 ed = entries[e + 3];
        float4 ta = load4(T + (size_t)ea.x * LDI + c0);
        float4 tb = load4(T + (size_t)eb.x * LDI + c0);
        float4 tc = load4(T + (size_t)ec.x * LDI + c0);
        float4 td = load4(T + (size_t)ed.x * LDI + c0);
        float wa = __uint_as_float(ea.y), wb = __uint_as_float(eb.y);
        float wc = __uint_as_float(ec.y), wd = __uint_as_float(ed.y);
        acc0.x = fmaf(wa, ta.x, acc0.x); acc0.y = fmaf(wa, ta.y, acc0.y);
        acc0.z = fmaf(wa, ta.z, acc0.z); acc0.w = fmaf(wa, ta.w, acc0.w);
        acc1.x = fmaf(wb, tb.x, acc1.x); acc1.y = fmaf(wb, tb.y, acc1.y);
        acc1.z = fmaf(wb, tb.z, acc1.z); acc1.w = fmaf(wb, tb.w, acc1.w);
        acc0.x = fmaf(wc, tc.x, acc0.x); acc0.y = fmaf(wc, tc.y, acc0.y);
        acc0.z = fmaf(wc, tc.z, acc0.z); acc0.w = fmaf(wc, tc.w, acc0.w);
        acc1.x = fmaf(wd, td.x, acc1.x); acc1.y = fmaf(wd, td.y, acc1.y);
        acc1.z = fmaf(wd, td.z, acc1.z); acc1.w = fmaf(wd, td.w, acc1.w);
    }
    for (; e < e1; ++e) {
        uint2 ea = entries[e];
        float4 ta = load4(T + (size_t)ea.x * LDI + c0);
        float wa = __uint_as_float(ea.y);
        acc0.x = fmaf(wa, ta.x, acc0.x); acc0.y = fmaf(wa, ta.y, acc0.y);
        acc0.z = fmaf(wa, ta.z, acc0.z); acc0.w = fmaf(wa, ta.w, acc0.w);
    }
    acc0.x += acc1.x; acc0.y += acc1.y; acc0.z += acc1.z; acc0.w += acc1.w;

    float* vp = &acc0.x;
    #pragma unroll
    for (int j = 0; j < 4; ++j) {
        if (BIAS && (c0 + j) < M) vp[j] += bias[c0 + j];
        if (RELU) vp[j] = fmaxf(vp[j], 0.f);
    }
    store4(out + (size_t)i * LDO + c0, acc0);
}

// ---------------- driver ----------------

extern "C" void kernel_launch(void* const* d_in, const int* in_sizes, int n_in,
                              void* d_out, int out_size, void* d_ws, size_t ws_size,
                              hipStream_t stream) {
    const float* x  = (const float*)d_in[0];
    const float* W1 = (const float*)d_in[1];
    const float* b1 = (const float*)d_in[2];
    const float* W2 = (const float*)d_in[3];
    const float* b2 = (const float*)d_in[4];
    const float* W3 = (const float*)d_in[5];
    const float* b3 = (const float*)d_in[6];
    const float* W4 = (const float*)d_in[7];
    const float* b4 = (const float*)d_in[8];
    const int* edge_index = (const int*)d_in[9];

    const int N = in_sizes[0] / 88;
    const int E = in_sizes[9] / 2;
    const int* src = edge_index;
    const int* dst = edge_index + E;

    const int nch = (E + CHUNK - 1) / CHUNK;            // 391
    const int bsz = (N + NB - 1) / NB;                  // 782
    const unsigned long long invB = ((1ull << 40) + bsz - 1) / bsz;

    char* p = (char*)d_ws;
    auto carve = [&](size_t bytes) { void* r = p; p += (bytes + 255) & ~(size_t)255; return r; };
    int*   cnt     = (int*)  carve((size_t)N * 4);
    int*   fillpos = (int*)  carve((size_t)N * 4);
    float* dinv    = (float*)carve((size_t)N * 4);
    int*   row_ptr = (int*)  carve((size_t)(N + 1) * 4);
    int*   bsum    = (int*)  carve(4096);
    int*   bcounts = (int*)  carve((size_t)nch * NB * 4);
    int*   ovf_cnt = (int*)  carve(256);
    uint2* ovf     = (uint2*)carve((size_t)OVF_CAP * 8);
    unsigned* bbuf = (unsigned*)carve((size_t)nch * NB * CAP * 4);
    uint2* entries = (uint2*)carve((size_t)E * 8);
    _Float16* hA   = (_Float16*)carve((size_t)N * 68 * 2);
    _Float16* hB   = (_Float16*)carve((size_t)N * 68 * 2);
    _Float16* hC   = (_Float16*)carve((size_t)N * 68 * 2);

    int gN = (N + BS - 1) / BS;

    k_zero  <<<gN, BS, 0, stream>>>(cnt, fillpos, ovf_cnt, N);
    k_bucket<<<nch, BS, 0, stream>>>(src, dst, cnt, bbuf, bcounts, ovf, ovf_cnt, E, invB, bsz);
    k_dinv  <<<gN, BS, 0, stream>>>(cnt, dinv, N);
    k_scan1 <<<gN, BS, 0, stream>>>(cnt, bsum, N);
    k_scan2 <<<1, 512, 0, stream>>>(bsum, gN);
    k_scan3 <<<gN, BS, 0, stream>>>(cnt, bsum, row_ptr, N);
    k_fill2 <<<NB, BS, 0, stream>>>(bbuf, bcounts, ovf, ovf_cnt, row_ptr, fillpos, dinv, entries, nch, bsz);

    auto agg_grid = [&](int CG) { return (N * CG + BS - 1) / BS; };

    // G1: x(f32,88) @ W1 -> hA(f16, ld68)
    k_gemm<float, 88, 65, 88, 68, false, false, _Float16><<<gN, BS, 0, stream>>>(x, W1, nullptr, hA, N);
    // A1: agg(hA) +b1 +relu -> hB(f16, ld68)
    k_agg<_Float16, _Float16, 65, 68, 68, 68, true, true><<<agg_grid(17), BS, 0, stream>>>(hA, hB, row_ptr, entries, dinv, b1, N);
    // G2: hB @ W2 -> hC(f16, ld64: 128B rows -> 2-line gathers)
    k_gemm<_Float16, 65, 50, 68, 64, false, false, _Float16><<<gN, BS, 0, stream>>>(hB, W2, nullptr, hC, N);
    // A2: agg(hC) +b2 -> hA(f16, ld64)
    k_agg<_Float16, _Float16, 50, 52, 64, 64, true, false><<<agg_grid(13), BS, 0, stream>>>(hC, hA, row_ptr, entries, dinv, b2, N);
    // A3: agg(hA) -> hB(f16, ld52)
    k_agg<_Float16, _Float16, 50, 52, 64, 52, false, false><<<agg_grid(13), BS, 0, stream>>>(hA, hB, row_ptr, entries, dinv, nullptr, N);
    // G3: hB @ W3 +b3 +relu -> hC(f16, ld68)
    k_gemm<_Float16, 50, 65, 52, 68, true, true, _Float16><<<gN, BS, 0, stream>>>(hB, W3, b3, hC, N);
    // A4: agg(hC) -> hA(f16, ld68)
    k_agg<_Float16, _Float16, 65, 68, 68, 68, false, false><<<agg_grid(17), BS, 0, stream>>>(hC, hA, row_ptr, entries, dinv, nullptr, N);
    // G4: hA @ W4 +b4 -> d_out(f32, ld88)
    k_gemm<_Float16, 65, 88, 68, 88, true, false, float><<<gN, BS, 0, stream>>>(hA, W4, b4, (float*)d_out, N);
}

// Round 8
// 560.994 us; speedup vs baseline: 1.1918x; 1.1918x over previous
//
#include <hip/hip_runtime.h>

#define BS 256
#define NB 256          // dst-range buckets (one block each in phases 2/3)
#define CHUNK 4096      // edges per phase-1 block
#define CAP 64          // slots per (chunk,bucket); Poisson(16), +12 sigma
#define LCAP 8192       // entries per bucket in LDS; Poisson(6250), +24 sigma

using half4 = __attribute__((ext_vector_type(4))) _Float16;

template<typename T>
__device__ __forceinline__ float4 load4(const T* p) {
    if constexpr (sizeof(T) == 4) {
        return *(const float4*)p;
    } else {
        half4 v = *(const half4*)p;
        return make_float4((float)v.x, (float)v.y, (float)v.z, (float)v.w);
    }
}
template<typename T>
__device__ __forceinline__ void store4(T* p, float4 v) {
    if constexpr (sizeof(T) == 4) {
        *(float4*)p = v;
    } else {
        half4 h = {(_Float16)v.x, (_Float16)v.y, (_Float16)v.z, (_Float16)v.w};
        *(half4*)p = h;
    }
}

// ---------------- CSR build ----------------

__global__ __launch_bounds__(BS) void k_zero1(int* a, int n) {
    int i = blockIdx.x * BS + threadIdx.x;
    if (i < n) a[i] = 0;
}

// Phase 1: bucket edges into block-private regions (packed doff<<17|src).
// No global atomics; writes are block-exclusive and slot-0-packed (dense).
__global__ __launch_bounds__(BS) void k_bucket(const int* __restrict__ src, const int* __restrict__ dst,
                                               unsigned* __restrict__ bbuf, int* __restrict__ bcounts,
                                               int E, unsigned long long invB, int bsz) {
    __shared__ int lcnt[NB];
    for (int t = threadIdx.x; t < NB; t += BS) lcnt[t] = 0;
    __syncthreads();
    int base_e = blockIdx.x * CHUNK;
    unsigned* mybuf = bbuf + (size_t)blockIdx.x * NB * CAP;
    #pragma unroll
    for (int j = 0; j < CHUNK / BS; ++j) {
        int e = base_e + j * BS + threadIdx.x;
        if (e < E) {
            int d = dst[e];
            int s = src[e];
            int b = (int)(((unsigned long long)(unsigned)d * invB) >> 40);
            int doff = d - b * bsz;                       // < 512 (9 bits)
            int pos = atomicAdd(&lcnt[b], 1);
            if (pos < CAP)                                // overflow impossible (+12 sigma)
                mybuf[b * CAP + pos] = ((unsigned)doff << 17) | (unsigned)s;
        }
    }
    __syncthreads();
    for (int t = threadIdx.x; t < NB; t += BS)
        bcounts[blockIdx.x * NB + t] = min(lcnt[t], CAP);
}

// Phase 2: per-bucket degree counts via LDS histogram; dense cnt writes.
__global__ __launch_bounds__(BS) void k_cnt(const unsigned* __restrict__ bbuf, const int* __restrict__ bcounts,
                                            int* __restrict__ cnt, int nch, int bsz, int N) {
    __shared__ int lhist[512];
    for (int t = threadIdx.x; t < 512; t += BS) lhist[t] = 0;
    __syncthreads();
    int b = blockIdx.x;
    int lo = b * bsz;
    int wid = threadIdx.x >> 6, lane = threadIdx.x & 63;
    for (int r = wid; r < nch; r += BS / 64) {
        int c = bcounts[r * NB + b];                      // wave-uniform
        const unsigned* seg = bbuf + ((size_t)r * NB + b) * CAP;
        for (int k = lane; k < c; k += 64)
            atomicAdd(&lhist[seg[k] >> 17], 1);
    }
    __syncthreads();
    int hi = min(N, lo + bsz);
    for (int t = threadIdx.x; t < hi - lo; t += BS) cnt[lo + t] = lhist[t];
}

__global__ __launch_bounds__(BS) void k_dinv(const int* __restrict__ cnt, float* __restrict__ dinv, int N) {
    int i = blockIdx.x * BS + threadIdx.x;
    if (i < N) dinv[i] = rsqrtf((float)(cnt[i] + 1));   // +1 = self-loop
}

__global__ __launch_bounds__(BS) void k_scan1(const int* __restrict__ cnt, int* __restrict__ bsum, int N) {
    __shared__ int s[BS];
    int i = blockIdx.x * BS + threadIdx.x;
    s[threadIdx.x] = (i < N) ? cnt[i] : 0;
    __syncthreads();
    for (int off = BS / 2; off > 0; off >>= 1) {
        if (threadIdx.x < off) s[threadIdx.x] += s[threadIdx.x + off];
        __syncthreads();
    }
    if (threadIdx.x == 0) bsum[blockIdx.x] = s[0];
}

__global__ __launch_bounds__(512) void k_scan2(int* bsum, int nb) {
    __shared__ int s[512];
    int t = threadIdx.x;
    int v = (t < nb) ? bsum[t] : 0;
    s[t] = v;
    __syncthreads();
    for (int off = 1; off < 512; off <<= 1) {
        int u = (t >= off) ? s[t - off] : 0;
        __syncthreads();
        s[t] += u;
        __syncthreads();
    }
    if (t < nb) bsum[t] = s[t] - v;   // exclusive of self
}

__global__ __launch_bounds__(BS) void k_scan3(const int* __restrict__ cnt, const int* __restrict__ boff,
                                              int* __restrict__ row_ptr, int N) {
    __shared__ int s[BS];
    int t = threadIdx.x;
    int i = blockIdx.x * BS + t;
    int v = (i < N) ? cnt[i] : 0;
    s[t] = v;
    __syncthreads();
    for (int off = 1; off < BS; off <<= 1) {
        int u = (t >= off) ? s[t - off] : 0;
        __syncthreads();
        s[t] += u;
        __syncthreads();
    }
    int base = boff[blockIdx.x];
    if (i < N) row_ptr[i] = base + s[t] - v;
    if (i == N - 1) row_ptr[N] = base + s[t];
}

// Phase 3: counting-sort each bucket's edges by dst in LDS, then stream the
// sorted entries to global with fully sequential coalesced stores.
__global__ __launch_bounds__(BS) void k_fill2(const unsigned* __restrict__ bbuf, const int* __restrict__ bcounts,
                                              const int* __restrict__ row_ptr, const float* __restrict__ dinv,
                                              uint2* __restrict__ entries,
                                              int nch, int bsz, int N) {
    extern __shared__ int sh[];
    int* cur      = sh;                 // bsz cursors (exclusive starts from row_ptr)
    int* ltot     = sh + 512;
    float* ldinv  = (float*)(sh + 516); // dinv[lo..hi)
    int* raw      = sh + 1032;          // LCAP packed
    int* sorted   = raw + LCAP;         // LCAP packed

    int b = blockIdx.x;
    int lo = b * bsz;
    int hi = min(N, lo + bsz);
    int gbase = row_ptr[lo];
    if (threadIdx.x == 0) *ltot = 0;
    for (int t = threadIdx.x; t < hi - lo; t += BS) {
        cur[t] = row_ptr[lo + t] - gbase;
        ldinv[t] = dinv[lo + t];
    }
    __syncthreads();

    // Pass A: gather this bucket's segments into raw[] (order irrelevant).
    int wid = threadIdx.x >> 6, lane = threadIdx.x & 63;
    for (int r = wid; r < nch; r += BS / 64) {
        int c = bcounts[r * NB + b];                      // wave-uniform
        int base = 0;
        if (lane == 0) base = atomicAdd(ltot, c);
        base = __shfl(base, 0);
        const unsigned* seg = bbuf + ((size_t)r * NB + b) * CAP;
        for (int k = lane; k < c; k += 64) {
            int p = base + k;
            if (p < LCAP) raw[p] = (int)seg[k];
        }
    }
    __syncthreads();
    int tot = min(*ltot, LCAP);

    // Pass B: counting-sort by doff via LDS cursors.
    for (int t = threadIdx.x; t < tot; t += BS) {
        unsigned u = (unsigned)raw[t];
        int doff = (int)(u >> 17);
        int p = atomicAdd(&cur[doff], 1);
        sorted[p] = (int)u;
    }
    __syncthreads();

    // Pass C: sequential write-out; entries[gbase+t] is d-sorted by construction.
    for (int t = threadIdx.x; t < tot; t += BS) {
        unsigned u = (unsigned)sorted[t];
        int s = (int)(u & 0x1FFFFu);
        int doff = (int)(u >> 17);
        float w = dinv[s] * ldinv[doff];
        entries[gbase + t] = make_uint2((unsigned)s, __float_as_uint(w));
    }
}

// ---------------- dense transform ----------------
// out[N, LDOUT(pad0)] = H[N, LDIN] @ W[K, M] (+bias)(+relu). Single pass,
// full-M accumulators; W in LDS read via same-address broadcast.
template<typename TIN, int K, int M, int LDIN, int LDOUT, bool BIAS, bool RELU, typename TOUT>
__global__ __launch_bounds__(BS) void k_gemm(const TIN* __restrict__ H, const float* __restrict__ Wg,
                                             const float* __restrict__ bias, TOUT* __restrict__ out, int N) {
    constexpr int M4 = (M + 3) & ~3;
    __shared__ float Wl[K * M4];
    for (int idx = threadIdx.x; idx < K * M4; idx += BS) {
        int k = idx / M4, m = idx - k * M4;
        Wl[idx] = (m < M) ? Wg[(size_t)k * M + m] : 0.f;
    }
    __syncthreads();

    int row = blockIdx.x * BS + threadIdx.x;
    bool ok = row < N;
    int rr = ok ? row : (N - 1);            // clamp: safe loads, masked stores
    const TIN* hp = H + (size_t)rr * LDIN;

    float acc[M4];
    #pragma unroll
    for (int m = 0; m < M4; ++m) acc[m] = 0.f;

    constexpr int K4 = K & ~3;
    #pragma unroll 2
    for (int k = 0; k < K4; k += 4) {
        float4 hv = load4(hp + k);
        const float h[4] = {hv.x, hv.y, hv.z, hv.w};
        #pragma unroll
        for (int j = 0; j < 4; ++j) {
            const float* wl = &Wl[(k + j) * M4];
            #pragma unroll
            for (int m = 0; m < M4; m += 4) {
                float4 w = *(const float4*)(wl + m);   // ds_read_b128 broadcast
                acc[m + 0] = fmaf(h[j], w.x, acc[m + 0]);
                acc[m + 1] = fmaf(h[j], w.y, acc[m + 1]);
                acc[m + 2] = fmaf(h[j], w.z, acc[m + 2]);
                acc[m + 3] = fmaf(h[j], w.w, acc[m + 3]);
            }
        }
    }
    #pragma unroll
    for (int k = K4; k < K; ++k) {
        float h = (float)hp[k];
        const float* wl = &Wl[k * M4];
        #pragma unroll
        for (int m = 0; m < M4; m += 4) {
            float4 w = *(const float4*)(wl + m);
            acc[m + 0] = fmaf(h, w.x, acc[m + 0]);
            acc[m + 1] = fmaf(h, w.y, acc[m + 1]);
            acc[m + 2] = fmaf(h, w.z, acc[m + 2]);
            acc[m + 3] = fmaf(h, w.w, acc[m + 3]);
        }
    }

    if (!ok) return;
    TOUT* op = out + (size_t)row * LDOUT;
    #pragma unroll
    for (int g = 0; g < LDOUT / 4; ++g) {
        int cb = 4 * g;
        float4 v;
        float* vp = &v.x;
        #pragma unroll
        for (int j = 0; j < 4; ++j) {
            int c = cb + j;
            float x = (c < M) ? acc[(c < M4) ? c : 0] : 0.f;
            if (BIAS && c < M) x += bias[c];
            if (RELU) x = fmaxf(x, 0.f);
            vp[j] = x;
        }
        store4(op + cb, v);
    }
}

// ---------------- normalized aggregation ----------------
// out[i,:] = dinv_i^2*T[i,:] + sum_e w_e * T[src_e,:]  (+bias)(+relu)
template<typename TIN, typename TOUT, int M, int M4, int LDI, int LDO, bool BIAS, bool RELU>
__global__ __launch_bounds__(BS) void k_agg(const TIN* __restrict__ T, TOUT* __restrict__ out,
                                            const int* __restrict__ row_ptr, const uint2* __restrict__ entries,
                                            const float* __restrict__ dinv, const float* __restrict__ bias,
                                            int N) {
    constexpr int CG = M4 / 4;
    int idx = blockIdx.x * BS + threadIdx.x;
    if (idx >= N * CG) return;
    int i  = idx / CG;                // const divisor -> magic mul
    int cg = idx - i * CG;
    int c0 = cg * 4;

    float di = dinv[i];
    float4 t0 = load4(T + (size_t)i * LDI + c0);
    float w0 = di * di;
    float4 acc0 = make_float4(w0 * t0.x, w0 * t0.y, w0 * t0.z, w0 * t0.w);
    float4 acc1 = make_float4(0.f, 0.f, 0.f, 0.f);

    int e0 = row_ptr[i], e1 = row_ptr[i + 1];
    int e = e0;
    for (; e + 3 < e1; e += 4) {
        uint2 ea = entries[e];
        uint2 eb = entries[e + 1];
        uint2 ec = entries[e + 2];
        uint2 ed = entries[e + 3];
        float4 ta = load4(T + (size_t)ea.x * LDI + c0);
        float4 tb = load4(T + (size_t)eb.x * LDI + c0);
        float4 tc = load4(T + (size_t)ec.x * LDI + c0);
        float4 td = load4(T + (size_t)ed.x * LDI + c0);
        float wa = __uint_as_float(ea.y), wb = __uint_as_float(eb.y);
        float wc = __uint_as_float(ec.y), wd = __uint_as_float(ed.y);
        acc0.x = fmaf(wa, ta.x, acc0.x); acc0.y = fmaf(wa, ta.y, acc0.y);
        acc0.z = fmaf(wa, ta.z, acc0.z); acc0.w = fmaf(wa, ta.w, acc0.w);
        acc1.x = fmaf(wb, tb.x, acc1.x); acc1.y = fmaf(wb, tb.y, acc1.y);
        acc1.z = fmaf(wb, tb.z, acc1.z); acc1.w = fmaf(wb, tb.w, acc1.w);
        acc0.x = fmaf(wc, tc.x, acc0.x); acc0.y = fmaf(wc, tc.y, acc0.y);
        acc0.z = fmaf(wc, tc.z, acc0.z); acc0.w = fmaf(wc, tc.w, acc0.w);
        acc1.x = fmaf(wd, td.x, acc1.x); acc1.y = fmaf(wd, td.y, acc1.y);
        acc1.z = fmaf(wd, td.z, acc1.z); acc1.w = fmaf(wd, td.w, acc1.w);
    }
    for (; e < e1; ++e) {
        uint2 ea = entries[e];
        float4 ta = load4(T + (size_t)ea.x * LDI + c0);
        float wa = __uint_as_float(ea.y);
        acc0.x = fmaf(wa, ta.x, acc0.x); acc0.y = fmaf(wa, ta.y, acc0.y);
        acc0.z = fmaf(wa, ta.z, acc0.z); acc0.w = fmaf(wa, ta.w, acc0.w);
    }
    acc0.x += acc1.x; acc0.y += acc1.y; acc0.z += acc1.z; acc0.w += acc1.w;

    float* vp = &acc0.x;
    #pragma unroll
    for (int j = 0; j < 4; ++j) {
        if (BIAS && (c0 + j) < M) vp[j] += bias[c0 + j];
        if (RELU) vp[j] = fmaxf(vp[j], 0.f);
    }
    store4(out + (size_t)i * LDO + c0, acc0);
}

// ---------------- driver ----------------

extern "C" void kernel_launch(void* const* d_in, const int* in_sizes, int n_in,
                              void* d_out, int out_size, void* d_ws, size_t ws_size,
                              hipStream_t stream) {
    const float* x  = (const float*)d_in[0];
    const float* W1 = (const float*)d_in[1];
    const float* b1 = (const float*)d_in[2];
    const float* W2 = (const float*)d_in[3];
    const float* b2 = (const float*)d_in[4];
    const float* W3 = (const float*)d_in[5];
    const float* b3 = (const float*)d_in[6];
    const float* W4 = (const float*)d_in[7];
    const float* b4 = (const float*)d_in[8];
    const int* edge_index = (const int*)d_in[9];

    const int N = in_sizes[0] / 88;
    const int E = in_sizes[9] / 2;
    const int* src = edge_index;
    const int* dst = edge_index + E;

    const int nch = (E + CHUNK - 1) / CHUNK;            // 391
    const int bsz = (N + NB - 1) / NB;                  // 391 (< 512, 9-bit doff)
    const unsigned long long invB = ((1ull << 40) + bsz - 1) / bsz;

    char* p = (char*)d_ws;
    auto carve = [&](size_t bytes) { void* r = p; p += (bytes + 255) & ~(size_t)255; return r; };
    int*   cnt     = (int*)  carve((size_t)N * 4);
    float* dinv    = (float*)carve((size_t)N * 4);
    int*   row_ptr = (int*)  carve((size_t)(N + 1) * 4);
    int*   bsum    = (int*)  carve(4096);
    int*   bcounts = (int*)  carve((size_t)nch * NB * 4);
    unsigned* bbuf = (unsigned*)carve((size_t)nch * NB * CAP * 4);
    uint2* entries = (uint2*)carve((size_t)E * 8);
    _Float16* hA   = (_Float16*)carve((size_t)N * 68 * 2);
    _Float16* hB   = (_Float16*)carve((size_t)N * 68 * 2);
    _Float16* hC   = (_Float16*)carve((size_t)N * 68 * 2);

    int gN = (N + BS - 1) / BS;

    k_zero1 <<<gN, BS, 0, stream>>>(cnt, N);
    k_bucket<<<nch, BS, 0, stream>>>(src, dst, bbuf, bcounts, E, invB, bsz);
    k_cnt   <<<NB, BS, 0, stream>>>(bbuf, bcounts, cnt, nch, bsz, N);
    k_dinv  <<<gN, BS, 0, stream>>>(cnt, dinv, N);
    k_scan1 <<<gN, BS, 0, stream>>>(cnt, bsum, N);
    k_scan2 <<<1, 512, 0, stream>>>(bsum, gN);
    k_scan3 <<<gN, BS, 0, stream>>>(cnt, bsum, row_ptr, N);
    size_t f2_lds = (size_t)(1032 + 2 * LCAP) * 4;      // cur/ltot/ldinv + raw + sorted
    k_fill2 <<<NB, BS, f2_lds, stream>>>(bbuf, bcounts, row_ptr, dinv, entries, nch, bsz, N);

    auto agg_grid = [&](int CG) { return (N * CG + BS - 1) / BS; };

    // G1: x(f32,88) @ W1 -> hA(f16, ld68)
    k_gemm<float, 88, 65, 88, 68, false, false, _Float16><<<gN, BS, 0, stream>>>(x, W1, nullptr, hA, N);
    // A1: agg(hA) +b1 +relu -> hB(f16, ld68)
    k_agg<_Float16, _Float16, 65, 68, 68, 68, true, true><<<agg_grid(17), BS, 0, stream>>>(hA, hB, row_ptr, entries, dinv, b1, N);
    // G2: hB @ W2 -> hC(f16, ld64: 128B rows -> exact 2-line gathers)
    k_gemm<_Float16, 65, 50, 68, 64, false, false, _Float16><<<gN, BS, 0, stream>>>(hB, W2, nullptr, hC, N);
    // A2: agg(hC) +b2 -> hA(f16, ld64)
    k_agg<_Float16, _Float16, 50, 52, 64, 64, true, false><<<agg_grid(13), BS, 0, stream>>>(hC, hA, row_ptr, entries, dinv, b2, N);
    // A3: agg(hA) -> hB(f16, ld52)
    k_agg<_Float16, _Float16, 50, 52, 64, 52, false, false><<<agg_grid(13), BS, 0, stream>>>(hA, hB, row_ptr, entries, dinv, nullptr, N);
    // G3: hB @ W3 +b3 +relu -> hC(f16, ld68)
    k_gemm<_Float16, 50, 65, 52, 68, true, true, _Float16><<<gN, BS, 0, stream>>>(hB, W3, b3, hC, N);
    // A4: agg(hC) -> hA(f16, ld68)
    k_agg<_Float16, _Float16, 65, 68, 68, 68, false, false><<<agg_grid(17), BS, 0, stream>>>(hC, hA, row_ptr, entries, dinv, nullptr, N);
    // G4: hA @ W4 +b4 -> d_out(f32, ld88)
    k_gemm<_Float16, 65, 88, 68, 88, true, false, float><<<gN, BS, 0, stream>>>(hA, W4, b4, (float*)d_out, N);
}

// Round 9
// 496.830 us; speedup vs baseline: 1.3457x; 1.1291x over previous
//
#include <hip/hip_runtime.h>

#define BS 256
#define FB 1024         // threads for bucket-parallel phases
#define NB 256          // dst-range buckets (one block each in phases 2/3)
#define CHUNK 4096      // edges per phase-1 block
#define CAP 64          // slots per (chunk,bucket); Poisson(16), +12 sigma
#define LCAP 8192       // entries per bucket in LDS; Poisson(6250), +24 sigma

using half4 = __attribute__((ext_vector_type(4))) _Float16;

template<typename T>
__device__ __forceinline__ float4 load4(const T* p) {
    if constexpr (sizeof(T) == 4) {
        return *(const float4*)p;
    } else {
        half4 v = *(const half4*)p;
        return make_float4((float)v.x, (float)v.y, (float)v.z, (float)v.w);
    }
}
template<typename T>
__device__ __forceinline__ void store4(T* p, float4 v) {
    if constexpr (sizeof(T) == 4) {
        *(float4*)p = v;
    } else {
        half4 h = {(_Float16)v.x, (_Float16)v.y, (_Float16)v.z, (_Float16)v.w};
        *(half4*)p = h;
    }
}

// ---------------- CSR build ----------------

__global__ __launch_bounds__(BS) void k_zero1(int* a, int n) {
    int i = blockIdx.x * BS + threadIdx.x;
    if (i < n) a[i] = 0;
}

// Phase 1: bucket edges into block-private regions (packed doff<<17|src).
// No global atomics; writes are block-exclusive and slot-0-packed (dense).
__global__ __launch_bounds__(BS) void k_bucket(const int* __restrict__ src, const int* __restrict__ dst,
                                               unsigned* __restrict__ bbuf, int* __restrict__ bcounts,
                                               int E, unsigned long long invB, int bsz) {
    __shared__ int lcnt[NB];
    for (int t = threadIdx.x; t < NB; t += BS) lcnt[t] = 0;
    __syncthreads();
    int base_e = blockIdx.x * CHUNK;
    unsigned* mybuf = bbuf + (size_t)blockIdx.x * NB * CAP;
    #pragma unroll
    for (int j = 0; j < CHUNK / BS; ++j) {
        int e = base_e + j * BS + threadIdx.x;
        if (e < E) {
            int d = dst[e];
            int s = src[e];
            int b = (int)(((unsigned long long)(unsigned)d * invB) >> 40);
            int doff = d - b * bsz;                       // < 512 (9 bits)
            int pos = atomicAdd(&lcnt[b], 1);
            if (pos < CAP)                                // overflow ~impossible (+12 sigma)
                mybuf[b * CAP + pos] = ((unsigned)doff << 17) | (unsigned)s;
        }
    }
    __syncthreads();
    for (int t = threadIdx.x; t < NB; t += BS)
        bcounts[blockIdx.x * NB + t] = min(lcnt[t], CAP);
}

// Phase 2: per-bucket degree counts. Slot-parallel: each thread strides over
// nch*CAP slots (seg = idx>>6 wave-uniform), fully independent loads.
__global__ __launch_bounds__(FB) void k_cnt(const unsigned* __restrict__ bbuf, const int* __restrict__ bcounts,
                                            int* __restrict__ cnt, int nch, int bsz, int N) {
    __shared__ int lhist[512];
    for (int t = threadIdx.x; t < 512; t += FB) lhist[t] = 0;
    __syncthreads();
    int b = blockIdx.x;
    int lo = b * bsz;
    int total = nch * CAP;
    for (int idx = threadIdx.x; idx < total; idx += FB) {
        int seg = idx >> 6, slot = idx & 63;              // CAP == 64
        int c = bcounts[seg * NB + b];                    // wave-uniform
        if (slot < c)
            atomicAdd(&lhist[bbuf[((size_t)seg * NB + b) * CAP + slot] >> 17], 1);
    }
    __syncthreads();
    int hi = min(N, lo + bsz);
    for (int t = threadIdx.x; t < hi - lo; t += FB) cnt[lo + t] = lhist[t];
}

__global__ __launch_bounds__(BS) void k_dinv(const int* __restrict__ cnt, float* __restrict__ dinv, int N) {
    int i = blockIdx.x * BS + threadIdx.x;
    if (i < N) dinv[i] = rsqrtf((float)(cnt[i] + 1));   // +1 = self-loop
}

__global__ __launch_bounds__(BS) void k_scan1(const int* __restrict__ cnt, int* __restrict__ bsum, int N) {
    __shared__ int s[BS];
    int i = blockIdx.x * BS + threadIdx.x;
    s[threadIdx.x] = (i < N) ? cnt[i] : 0;
    __syncthreads();
    for (int off = BS / 2; off > 0; off >>= 1) {
        if (threadIdx.x < off) s[threadIdx.x] += s[threadIdx.x + off];
        __syncthreads();
    }
    if (threadIdx.x == 0) bsum[blockIdx.x] = s[0];
}

__global__ __launch_bounds__(512) void k_scan2(int* bsum, int nb) {
    __shared__ int s[512];
    int t = threadIdx.x;
    int v = (t < nb) ? bsum[t] : 0;
    s[t] = v;
    __syncthreads();
    for (int off = 1; off < 512; off <<= 1) {
        int u = (t >= off) ? s[t - off] : 0;
        __syncthreads();
        s[t] += u;
        __syncthreads();
    }
    if (t < nb) bsum[t] = s[t] - v;   // exclusive of self
}

__global__ __launch_bounds__(BS) void k_scan3(const int* __restrict__ cnt, const int* __restrict__ boff,
                                              int* __restrict__ row_ptr, int N) {
    __shared__ int s[BS];
    int t = threadIdx.x;
    int i = blockIdx.x * BS + t;
    int v = (i < N) ? cnt[i] : 0;
    s[t] = v;
    __syncthreads();
    for (int off = 1; off < BS; off <<= 1) {
        int u = (t >= off) ? s[t - off] : 0;
        __syncthreads();
        s[t] += u;
        __syncthreads();
    }
    int base = boff[blockIdx.x];
    if (i < N) row_ptr[i] = base + s[t] - v;
    if (i == N - 1) row_ptr[N] = base + s[t];
}

// Phase 3: slot-parallel counting-sort straight into LDS (no staging pass),
// then stream sorted entries to global with sequential coalesced stores.
__global__ __launch_bounds__(FB) void k_fill2(const unsigned* __restrict__ bbuf, const int* __restrict__ bcounts,
                                              const int* __restrict__ row_ptr, const float* __restrict__ dinv,
                                              uint2* __restrict__ entries,
                                              int nch, int bsz, int N) {
    __shared__ int cur[512];
    __shared__ float ldinv[512];
    __shared__ unsigned sorted[LCAP];

    int b = blockIdx.x;
    int lo = b * bsz;
    int hi = min(N, lo + bsz);
    int gbase = row_ptr[lo];
    int tot = row_ptr[hi] - gbase;
    for (int t = threadIdx.x; t < hi - lo; t += FB) {
        cur[t] = row_ptr[lo + t] - gbase;
        ldinv[t] = dinv[lo + t];
    }
    __syncthreads();

    // Merged gather + counting-sort: independent loads, deep pipelining.
    int total = nch * CAP;
    for (int idx = threadIdx.x; idx < total; idx += FB) {
        int seg = idx >> 6, slot = idx & 63;              // CAP == 64
        int c = bcounts[seg * NB + b];                    // wave-uniform
        if (slot < c) {
            unsigned u = bbuf[((size_t)seg * NB + b) * CAP + slot];
            int p = atomicAdd(&cur[u >> 17], 1);
            if (p < LCAP) sorted[p] = u;
        }
    }
    __syncthreads();

    // Sequential write-out; entries[gbase+t] is d-sorted by construction.
    for (int t = threadIdx.x; t < tot; t += FB) {
        unsigned u = sorted[t];
        int s = (int)(u & 0x1FFFFu);
        int doff = (int)(u >> 17);
        float w = dinv[s] * ldinv[doff];
        entries[gbase + t] = make_uint2((unsigned)s, __float_as_uint(w));
    }
}

// ---------------- dense transform ----------------
// out[N, LDOUT(pad0)] = H[N, LDIN] @ W[K, M] (+bias)(+relu). Single pass,
// full-M accumulators; W in LDS read via same-address broadcast.
template<typename TIN, int K, int M, int LDIN, int LDOUT, bool BIAS, bool RELU, typename TOUT>
__global__ __launch_bounds__(BS) void k_gemm(const TIN* __restrict__ H, const float* __restrict__ Wg,
                                             const float* __restrict__ bias, TOUT* __restrict__ out, int N) {
    constexpr int M4 = (M + 3) & ~3;
    __shared__ float Wl[K * M4];
    for (int idx = threadIdx.x; idx < K * M4; idx += BS) {
        int k = idx / M4, m = idx - k * M4;
        Wl[idx] = (m < M) ? Wg[(size_t)k * M + m] : 0.f;
    }
    __syncthreads();

    int row = blockIdx.x * BS + threadIdx.x;
    bool ok = row < N;
    int rr = ok ? row : (N - 1);            // clamp: safe loads, masked stores
    const TIN* hp = H + (size_t)rr * LDIN;

    float acc[M4];
    #pragma unroll
    for (int m = 0; m < M4; ++m) acc[m] = 0.f;

    constexpr int K4 = K & ~3;
    #pragma unroll 2
    for (int k = 0; k < K4; k += 4) {
        float4 hv = load4(hp + k);
        const float h[4] = {hv.x, hv.y, hv.z, hv.w};
        #pragma unroll
        for (int j = 0; j < 4; ++j) {
            const float* wl = &Wl[(k + j) * M4];
            #pragma unroll
            for (int m = 0; m < M4; m += 4) {
                float4 w = *(const float4*)(wl + m);   // ds_read_b128 broadcast
                acc[m + 0] = fmaf(h[j], w.x, acc[m + 0]);
                acc[m + 1] = fmaf(h[j], w.y, acc[m + 1]);
                acc[m + 2] = fmaf(h[j], w.z, acc[m + 2]);
                acc[m + 3] = fmaf(h[j], w.w, acc[m + 3]);
            }
        }
    }
    #pragma unroll
    for (int k = K4; k < K; ++k) {
        float h = (float)hp[k];
        const float* wl = &Wl[k * M4];
        #pragma unroll
        for (int m = 0; m < M4; m += 4) {
            float4 w = *(const float4*)(wl + m);
            acc[m + 0] = fmaf(h, w.x, acc[m + 0]);
            acc[m + 1] = fmaf(h, w.y, acc[m + 1]);
            acc[m + 2] = fmaf(h, w.z, acc[m + 2]);
            acc[m + 3] = fmaf(h, w.w, acc[m + 3]);
        }
    }

    if (!ok) return;
    TOUT* op = out + (size_t)row * LDOUT;
    #pragma unroll
    for (int g = 0; g < LDOUT / 4; ++g) {
        int cb = 4 * g;
        float4 v;
        float* vp = &v.x;
        #pragma unroll
        for (int j = 0; j < 4; ++j) {
            int c = cb + j;
            float x = (c < M) ? acc[(c < M4) ? c : 0] : 0.f;
            if (BIAS && c < M) x += bias[c];
            if (RELU) x = fmaxf(x, 0.f);
            vp[j] = x;
        }
        store4(op + cb, v);
    }
}

// ---------------- normalized aggregation ----------------
// out[i,:] = dinv_i^2*T[i,:] + sum_e w_e * T[src_e,:]  (+bias)(+relu)
template<typename TIN, typename TOUT, int M, int M4, int LDI, int LDO, bool BIAS, bool RELU>
__global__ __launch_bounds__(BS) void k_agg(const TIN* __restrict__ T, TOUT* __restrict__ out,
                                            const int* __restrict__ row_ptr, const uint2* __restrict__ entries,
                                            const float* __restrict__ dinv, const float* __restrict__ bias,
                                            int N) {
    constexpr int CG = M4 / 4;
    int idx = blockIdx.x * BS + threadIdx.x;
    if (idx >= N * CG) return;
    int i  = idx / CG;                // const divisor -> magic mul
    int cg = idx - i * CG;
    int c0 = cg * 4;

    float di = dinv[i];
    float4 t0 = load4(T + (size_t)i * LDI + c0);
    float w0 = di * di;
    float4 acc0 = make_float4(w0 * t0.x, w0 * t0.y, w0 * t0.z, w0 * t0.w);
    float4 acc1 = make_float4(0.f, 0.f, 0.f, 0.f);

    int e0 = row_ptr[i], e1 = row_ptr[i + 1];
    int e = e0;
    for (; e + 3 < e1; e += 4) {
        uint2 ea = entries[e];
        uint2 eb = entries[e + 1];
        uint2 ec = entries[e + 2];
        uint2 ed = entries[e + 3];
        float4 ta = load4(T + (size_t)ea.x * LDI + c0);
        float4 tb = load4(T + (size_t)eb.x * LDI + c0);
        float4 tc = load4(T + (size_t)ec.x * LDI + c0);
        float4 td = load4(T + (size_t)ed.x * LDI + c0);
        float wa = __uint_as_float(ea.y), wb = __uint_as_float(eb.y);
        float wc = __uint_as_float(ec.y), wd = __uint_as_float(ed.y);
        acc0.x = fmaf(wa, ta.x, acc0.x); acc0.y = fmaf(wa, ta.y, acc0.y);
        acc0.z = fmaf(wa, ta.z, acc0.z); acc0.w = fmaf(wa, ta.w, acc0.w);
        acc1.x = fmaf(wb, tb.x, acc1.x); acc1.y = fmaf(wb, tb.y, acc1.y);
        acc1.z = fmaf(wb, tb.z, acc1.z); acc1.w = fmaf(wb, tb.w, acc1.w);
        acc0.x = fmaf(wc, tc.x, acc0.x); acc0.y = fmaf(wc, tc.y, acc0.y);
        acc0.z = fmaf(wc, tc.z, acc0.z); acc0.w = fmaf(wc, tc.w, acc0.w);
        acc1.x = fmaf(wd, td.x, acc1.x); acc1.y = fmaf(wd, td.y, acc1.y);
        acc1.z = fmaf(wd, td.z, acc1.z); acc1.w = fmaf(wd, td.w, acc1.w);
    }
    for (; e < e1; ++e) {
        uint2 ea = entries[e];
        float4 ta = load4(T + (size_t)ea.x * LDI + c0);
        float wa = __uint_as_float(ea.y);
        acc0.x = fmaf(wa, ta.x, acc0.x); acc0.y = fmaf(wa, ta.y, acc0.y);
        acc0.z = fmaf(wa, ta.z, acc0.z); acc0.w = fmaf(wa, ta.w, acc0.w);
    }
    acc0.x += acc1.x; acc0.y += acc1.y; acc0.z += acc1.z; acc0.w += acc1.w;

    float* vp = &acc0.x;
    #pragma unroll
    for (int j = 0; j < 4; ++j) {
        if (BIAS && (c0 + j) < M) vp[j] += bias[c0 + j];
        if (RELU) vp[j] = fmaxf(vp[j], 0.f);
    }
    store4(out + (size_t)i * LDO + c0, acc0);
}

// ---------------- driver ----------------

extern "C" void kernel_launch(void* const* d_in, const int* in_sizes, int n_in,
                              void* d_out, int out_size, void* d_ws, size_t ws_size,
                              hipStream_t stream) {
    const float* x  = (const float*)d_in[0];
    const float* W1 = (const float*)d_in[1];
    const float* b1 = (const float*)d_in[2];
    const float* W2 = (const float*)d_in[3];
    const float* b2 = (const float*)d_in[4];
    const float* W3 = (const float*)d_in[5];
    const float* b3 = (const float*)d_in[6];
    const float* W4 = (const float*)d_in[7];
    const float* b4 = (const float*)d_in[8];
    const int* edge_index = (const int*)d_in[9];

    const int N = in_sizes[0] / 88;
    const int E = in_sizes[9] / 2;
    const int* src = edge_index;
    const int* dst = edge_index + E;

    const int nch = (E + CHUNK - 1) / CHUNK;            // 391
    const int bsz = (N + NB - 1) / NB;                  // 391 (< 512, 9-bit doff)
    const unsigned long long invB = ((1ull << 40) + bsz - 1) / bsz;

    char* p = (char*)d_ws;
    auto carve = [&](size_t bytes) { void* r = p; p += (bytes + 255) & ~(size_t)255; return r; };
    int*   cnt     = (int*)  carve((size_t)N * 4);
    float* dinv    = (float*)carve((size_t)N * 4);
    int*   row_ptr = (int*)  carve((size_t)(N + 1) * 4);
    int*   bsum    = (int*)  carve(4096);
    int*   bcounts = (int*)  carve((size_t)nch * NB * 4);
    unsigned* bbuf = (unsigned*)carve((size_t)nch * NB * CAP * 4);
    uint2* entries = (uint2*)carve((size_t)E * 8);
    _Float16* hA   = (_Float16*)carve((size_t)N * 68 * 2);
    _Float16* hB   = (_Float16*)carve((size_t)N * 68 * 2);
    _Float16* hC   = (_Float16*)carve((size_t)N * 68 * 2);

    int gN = (N + BS - 1) / BS;

    k_zero1 <<<gN, BS, 0, stream>>>(cnt, N);
    k_bucket<<<nch, BS, 0, stream>>>(src, dst, bbuf, bcounts, E, invB, bsz);
    k_cnt   <<<NB, FB, 0, stream>>>(bbuf, bcounts, cnt, nch, bsz, N);
    k_dinv  <<<gN, BS, 0, stream>>>(cnt, dinv, N);
    k_scan1 <<<gN, BS, 0, stream>>>(cnt, bsum, N);
    k_scan2 <<<1, 512, 0, stream>>>(bsum, gN);
    k_scan3 <<<gN, BS, 0, stream>>>(cnt, bsum, row_ptr, N);
    k_fill2 <<<NB, FB, 0, stream>>>(bbuf, bcounts, row_ptr, dinv, entries, nch, bsz, N);

    auto agg_grid = [&](int CG) { return (N * CG + BS - 1) / BS; };

    // G1: x(f32,88) @ W1 -> hA(f16, ld68)
    k_gemm<float, 88, 65, 88, 68, false, false, _Float16><<<gN, BS, 0, stream>>>(x, W1, nullptr, hA, N);
    // A1: agg(hA) +b1 +relu -> hB(f16, ld68)
    k_agg<_Float16, _Float16, 65, 68, 68, 68, true, true><<<agg_grid(17), BS, 0, stream>>>(hA, hB, row_ptr, entries, dinv, b1, N);
    // G2: hB @ W2 -> hC(f16, ld64: 128B rows -> exact 2-line gathers)
    k_gemm<_Float16, 65, 50, 68, 64, false, false, _Float16><<<gN, BS, 0, stream>>>(hB, W2, nullptr, hC, N);
    // A2: agg(hC) +b2 -> hA(f16, ld64)
    k_agg<_Float16, _Float16, 50, 52, 64, 64, true, false><<<agg_grid(13), BS, 0, stream>>>(hC, hA, row_ptr, entries, dinv, b2, N);
    // A3: agg(hA) -> hB(f16, ld52)
    k_agg<_Float16, _Float16, 50, 52, 64, 52, false, false><<<agg_grid(13), BS, 0, stream>>>(hA, hB, row_ptr, entries, dinv, nullptr, N);
    // G3: hB @ W3 +b3 +relu -> hC(f16, ld68)
    k_gemm<_Float16, 50, 65, 52, 68, true, true, _Float16><<<gN, BS, 0, stream>>>(hB, W3, b3, hC, N);
    // A4: agg(hC) -> hA(f16, ld68)
    k_agg<_Float16, _Float16, 65, 68, 68, 68, false, false><<<agg_grid(17), BS, 0, stream>>>(hC, hA, row_ptr, entries, dinv, nullptr, N);
    // G4: hA @ W4 +b4 -> d_out(f32, ld88)
    k_gemm<_Float16, 65, 88, 68, 88, true, false, float><<<gN, BS, 0, stream>>>(hA, W4, b4, (float*)d_out, N);
}